// Round 1
// baseline (375.665 us; speedup 1.0000x reference)
//
#include <hip/hip_runtime.h>
#include <stdint.h>

// ---------------- problem constants ----------------
#define BATCH 16
#define NCLS 80
#define NPOS 21824            // 16384+4096+1024+256+64
#define POOLN 3320            // 1000+1000+1000+256+64
#define MAXDET 100

// superset segment capacities (multiples of 8)
#define CAP0 4096
#define CAP1 2432
#define CAP2 1024
#define C34 320
#define CAP34 320
#define SEG1 (CAP0)                    // 4096
#define SEG2 (CAP0 + CAP1)             // 6528
#define SEG3 (CAP0 + CAP1 + CAP2)      // 7552
#define CAPTOT (SEG3 + CAP34)          // 7872

#define DEC_BPI 341                    // 21824/64 anchors-per-block blocks per image
#define GATHER_BPI 16                  // 16 x 1344 = 21504 anchors (levels 0..2)
#define GATHER_CHUNK 1344              // multiple of 64 -> wave-uniform level
#define POS_BPI 13                     // 13 x 256 = 3328 >= 3320 pool elements

#define NBINS 4096                     // digit = nsb >> 20 (12-bit key prefix)
#define HIST_TPI 11                    // hist tasks per image: 8(l0) + 2(l1) + 1(l2)

__device__ const int d_lvl_off[5] = {0, 16384, 20480, 21504, 21760};
__device__ const int d_lvl_hw[5]  = {16384, 4096, 1024, 256, 64};

struct Ptrs { const float* p[20]; };

__device__ __forceinline__ void map_lvl(int r, int& level, int& hw) {
  if      (r < 16384) { level = 0; hw = r; }
  else if (r < 20480) { level = 1; hw = r - 16384; }
  else if (r < 21504) { level = 2; hw = r - 20480; }
  else if (r < 21760) { level = 3; hw = r - 21504; }
  else                { level = 4; hw = r - 21760; }
}

// key = (nsb)<<32 | (level<<20) | hw with nsb = ~score_bits; ascending ==
// (score desc, level asc, idx asc). Unique per image; ~0ULL is a strictly-greater
// sentinel. digit = nsb >> 20 is a 12-bit key PREFIX -> {digit <= B} downward-closed.

// ---------------- kernel 1: decode (exact R6 structure, proven ~70 us) ----------------
__global__ __launch_bounds__(256) void decode_kernel(Ptrs args, uint4* __restrict__ dec,
                                                     unsigned long long* __restrict__ gbuf,
                                                     int* __restrict__ gcnt,
                                                     unsigned* __restrict__ sbuf) {
  int b  = blockIdx.x / DEC_BPI;
  int bb = blockIdx.x - b * DEC_BPI;
  int t = threadIdx.x;
  if (bb == 0 && t < 3) gcnt[b * 3 + t] = 0;

  int flat0 = bb * 64;                      // level boundaries are all multiples of 64
  int level, hw0;
  map_lvl(flat0, level, hw0);
  int HW = d_lvl_hw[level];
  int aoff = t >> 2, part = t & 3;
  int hw = hw0 + aoff;
  long abase = (long)b * HW + hw;

  const float* cls = args.p[level * 4 + 0];
  const float* reg = args.p[level * 4 + 1];
  const float* ctr = args.p[level * 4 + 2];
  const float* pos = args.p[level * 4 + 3];

  const float4* c4 = (const float4*)(cls + abase * NCLS) + part * 5;
  float4 v0 = c4[0], v1 = c4[1], v2 = c4[2], v3 = c4[3], v4 = c4[4];

  float m = -1e30f; int am = 0;
  int cb = part * 20;
#define CHK(val, j) if ((val) > m) { m = (val); am = cb + (j); }
  CHK(v0.x, 0)  CHK(v0.y, 1)  CHK(v0.z, 2)  CHK(v0.w, 3)
  CHK(v1.x, 4)  CHK(v1.y, 5)  CHK(v1.z, 6)  CHK(v1.w, 7)
  CHK(v2.x, 8)  CHK(v2.y, 9)  CHK(v2.z, 10) CHK(v2.w, 11)
  CHK(v3.x, 12) CHK(v3.y, 13) CHK(v3.z, 14) CHK(v3.w, 15)
  CHK(v4.x, 16) CHK(v4.y, 17) CHK(v4.z, 18) CHK(v4.w, 19)
#undef CHK
#pragma unroll
  for (int d = 1; d <= 2; d <<= 1) {
    float om = __shfl_xor(m, d, 64);
    int   oa = __shfl_xor(am, d, 64);
    if (om > m || (om == m && oa < am)) { m = om; am = oa; }
  }

  if (part == 0) {
    float4 rg = *(const float4*)(reg + abase * 4);
    float  ct = ctr[abase];
    float2 ps = ((const float2*)pos)[abase];

    float e0 = expf(rg.x), e1 = expf(rg.y), e2 = expf(rg.z), e3 = expf(rg.w);
    int x1 = (int)(ps.x - e0);   // C truncation == .astype(int32)
    int y1 = (int)(ps.y - e1);
    int x2 = (int)(ps.x + e2);
    int y2 = (int)(ps.y + e3);
    x1 = max(x1, 0); y1 = max(y1, 0);
    x2 = min(x2, 1023); y2 = min(y2, 1023);

    float sigm = 1.0f / (1.0f + expf(-m));
    float sigc = 1.0f / (1.0f + expf(-ct));
    float score = sqrtf(sigm * sigc);

    uint4 e;
    e.x = __float_as_uint(score);
    e.y = (unsigned)am;
    e.z = (unsigned)(x1 & 0xFFFF) | ((unsigned)y1 << 16);
    e.w = (unsigned)(x2 & 0xFFFF) | ((unsigned)y2 << 16);
    dec[b * NPOS + flat0 + aoff] = e;

    unsigned nsb = ~e.x;
    sbuf[b * NPOS + flat0 + aoff] = nsb;
    if (level >= 3) {    // deterministic slots for complete levels 3/4
      unsigned long long key =
          ((unsigned long long)nsb << 32) | (unsigned)((level << 20) | hw);
      gbuf[(size_t)b * CAPTOT + SEG3 + ((level == 3) ? hw : 256 + hw)] = key;
    }
  }
}

// ---------------- kernel 2: wide histogram (LDS-local, merge nonzero bins) ------
__global__ __launch_bounds__(256) void hist_kernel(const unsigned* __restrict__ sbuf,
                                                   unsigned* __restrict__ ghist) {
  __shared__ unsigned h[NBINS];
  int img = blockIdx.x / HIST_TPI, task = blockIdx.x % HIST_TPI;
  int level, start, n;
  if      (task < 8)  { level = 0; start = task * 2048;       n = 2048; }
  else if (task < 10) { level = 1; start = (task - 8) * 2048; n = 2048; }
  else                { level = 2; start = 0;                 n = 1024; }
  int tid = threadIdx.x;

  for (int i = tid; i < NBINS; i += 256) h[i] = 0;
  __syncthreads();
  const unsigned* base = sbuf + img * NPOS + d_lvl_off[level] + start;
  for (int i = tid; i < n; i += 256)
    atomicAdd(&h[base[i] >> 20], 1u);
  __syncthreads();
  unsigned* gh = ghist + (unsigned)(img * 3 + level) * NBINS;
  for (int i = tid; i < NBINS; i += 256) {
    unsigned v = h[i];
    if (v) atomicAdd(&gh[i], v);
  }
}

// ---------------- kernel 3: cutoff (parallel scan; proven R7 logic, 4096 bins) ----
__global__ __launch_bounds__(256) void cutoff_kernel(const unsigned* __restrict__ ghist,
                                                     int* __restrict__ bcut) {
  __shared__ unsigned wpart[4];
  __shared__ int shB;
  int img = blockIdx.x / 3, level = blockIdx.x % 3;
  const unsigned* h = ghist + (unsigned)(img * 3 + level) * NBINS;
  int tid = threadIdx.x, lane = tid & 63, wv = tid >> 6;

  unsigned hl[16];
  unsigned s = 0;
#pragma unroll
  for (int k = 0; k < 16; ++k) { hl[k] = h[16 * tid + k]; s += hl[k]; }
  unsigned incl = s;
  for (int d = 1; d < 64; d <<= 1) {
    unsigned v = __shfl_up(incl, d, 64);
    if (lane >= d) incl += v;
  }
  if (lane == 63) wpart[wv] = incl;
  __syncthreads();
  unsigned woff = 0;
  for (int w = 0; w < wv; ++w) woff += wpart[w];
  unsigned excl = woff + incl - s;
  if (excl < 1000u && excl + s >= 1000u) {       // unique crossing thread (N >= 1000)
    unsigned cum = excl; int B = NBINS - 1;
#pragma unroll
    for (int k = 0; k < 16; ++k) {
      cum += hl[k];
      if (cum >= 1000u) { B = 16 * tid + k; break; }
    }
    shB = B;
  }
  __syncthreads();
  if (tid == 0) bcut[img * 3 + level] = shB;
}

// ---------------- kernel 4: wide gather -> single gbuf layout (proven R7) ------
__global__ __launch_bounds__(256) void gather_kernel(const unsigned* __restrict__ sbuf,
                                                     const int* __restrict__ bcut,
                                                     unsigned long long* __restrict__ gbuf,
                                                     int* __restrict__ gcnt) {
  int img = blockIdx.x / GATHER_BPI, bb = blockIdx.x % GATHER_BPI;
  int tid = threadIdx.x, lane = tid & 63;
  int start = bb * GATHER_CHUNK;
  int b0 = bcut[img * 3 + 0], b1 = bcut[img * 3 + 1], b2 = bcut[img * 3 + 2];
  unsigned long long* gb = gbuf + (size_t)img * CAPTOT;

  for (int j = start + tid; j < start + GATHER_CHUNK; j += 256) {
    int level, hw;
    map_lvl(j, level, hw);                       // level wave-uniform (64-aligned groups)
    unsigned nsb = sbuf[img * NPOS + j];
    bool sel = (int)(nsb >> 20) <= ((level == 0) ? b0 : (level == 1) ? b1 : b2);
    unsigned long long msk = __ballot(sel);
    if (msk) {
      int nsel = __popcll(msk);
      int bas = 0;
      if (lane == 0) bas = atomicAdd(&gcnt[img * 3 + level], nsel);
      bas = __shfl(bas, 0, 64);
      if (sel) {
        int p = bas + __popcll(msk & ((1ULL << lane) - 1ULL));
        int cap   = (level == 0) ? CAP0 : (level == 1) ? CAP1 : CAP2;
        int sbase = (level == 0) ? 0    : (level == 1) ? SEG1 : SEG2;
        unsigned long long key =
            ((unsigned long long)nsb << 32) | (unsigned)((level << 20) | hw);
        if (p < cap) gb[sbase + p] = key;
      }
    }
  }
}

// ---------------- kernel 5a: per-(image,segment) in-LDS bitonic sort ----------
// Replaces the O(N^2) counting rank. Keys are unique per image; ~0ULL sentinels
// (strictly greater than any real key: real keys have level<=4 in low bits) pad
// each segment to the next pow2. Sorted segment written back in place to gbuf.
// Sorted order == exact (score desc, level asc, idx asc) within the segment.
__global__ __launch_bounds__(256) void sort_kernel(unsigned long long* __restrict__ gbuf,
                                                   const int* __restrict__ gcnt) {
  __shared__ unsigned long long sk[4096];        // 32 KiB: max segment pad
  int img = blockIdx.x >> 2, sg = blockIdx.x & 3;
  int tid = threadIdx.x;
  unsigned long long* gb = gbuf + (size_t)img * CAPTOT;

  int base, cap;
  if      (sg == 0) { base = 0;    cap = CAP0; }
  else if (sg == 1) { base = SEG1; cap = CAP1; }
  else if (sg == 2) { base = SEG2; cap = CAP2; }
  else              { base = SEG3; cap = C34;  }
  int c = (sg < 3) ? min(gcnt[img * 3 + sg], cap) : C34;

  int P = 512;                                   // pow2 pad (block-uniform)
  while (P < c) P <<= 1;

  for (int i = tid; i < P; i += 256)
    sk[i] = (i < c) ? gb[base + i] : ~0ULL;
  __syncthreads();

  for (int k = 2; k <= P; k <<= 1) {
    for (int j = k >> 1; j > 0; j >>= 1) {
      for (int p = tid; p < (P >> 1); p += 256) {
        int i  = ((p & ~(j - 1)) << 1) | (p & (j - 1));   // bit j of i is clear
        int mi = i | j;
        unsigned long long a = sk[i], b = sk[mi];
        if ((a > b) == ((i & k) == 0)) { sk[i] = b; sk[mi] = a; }
      }
      __syncthreads();
    }
  }

  for (int i = tid; i < c; i += 256) gb[base + i] = sk[i];
}

// ---------------- kernel 5b: position via binary search -> sorted pool --------
// One thread per pool element (t, i) with i < min(c_t,1000)  ==  old sel set
// (sorted index == old own-segment less-than count). pos = i + sum over other
// segments of min(lower_bound(seg, key), 1000)  ==  old sum of min(n_seg,1000).
__device__ __forceinline__ int lbound(const unsigned long long* __restrict__ a,
                                      int n, unsigned long long x) {
  int lo = 0, len = n;
  while (len > 0) {
    int half = len >> 1;
    int mid = lo + half;
    if (a[mid] < x) { lo = mid + 1; len -= half + 1; }
    else            { len = half; }
  }
  return lo;
}

__global__ __launch_bounds__(256) void pos_kernel(const unsigned long long* __restrict__ gbuf,
                                                  const int* __restrict__ gcnt,
                                                  unsigned long long* __restrict__ pool) {
  int img = blockIdx.x / POS_BPI, bb = blockIdx.x % POS_BPI;
  int e = bb * 256 + threadIdx.x;
  const unsigned long long* gb = gbuf + (size_t)img * CAPTOT;

  int c0 = min(gcnt[img * 3 + 0], CAP0);
  int c1 = min(gcnt[img * 3 + 1], CAP1);
  int c2 = min(gcnt[img * 3 + 2], CAP2);
  int m0 = min(c0, 1000), m1 = min(c1, 1000), m2 = min(c2, 1000);
  int tot = m0 + m1 + m2 + C34;
  if (e >= tot) return;

  int t, i;
  if      (e < m0)           { t = 0; i = e; }
  else if (e < m0 + m1)      { t = 1; i = e - m0; }
  else if (e < m0 + m1 + m2) { t = 2; i = e - m0 - m1; }
  else                       { t = 3; i = e - m0 - m1 - m2; }

  const int off[4] = {0, SEG1, SEG2, SEG3};
  const int cc[4]  = {c0, c1, c2, C34};

  unsigned long long key = gb[off[t] + i];
  int pos = i;                                   // own-segment term: min(rank,1000)=i
#pragma unroll
  for (int u = 0; u < 4; ++u) {
    if (u == t) continue;
    pos += min(lbound(gb + off[u], cc[u], key), 1000);
  }
  pool[img * POOLN + pos] = key;
}

// ---------------- kernel 6: per-image greedy NMS + output (bit-identical, proven) --
__global__ __launch_bounds__(64) void nms_kernel(const uint4* __restrict__ dec,
                                                 const unsigned long long* __restrict__ pool,
                                                 float* __restrict__ out) {
  __shared__ float          s_score[POOLN];
  __shared__ unsigned short s_cls[POOLN];
  __shared__ uint2          s_box[POOLN];
  int img = blockIdx.x;
  int lane = threadIdx.x;

  for (int r = lane; r < POOLN; r += 64) {
    unsigned long long key = pool[img * POOLN + r];
    unsigned low = (unsigned)key;
    int level = (low >> 20) & 7;
    int idx = low & 0xFFFFF;
    uint4 e = dec[img * NPOS + d_lvl_off[level] + idx];
    s_score[r] = __uint_as_float(e.x);
    s_cls[r]   = (unsigned short)e.y;
    s_box[r]   = make_uint2(e.z, e.w);
  }
  __syncthreads();

  float* out_s = out + img * MAXDET;
  float* out_c = out + BATCH * MAXDET + img * MAXDET;
  float* out_b = out + 2 * BATCH * MAXDET + img * MAXDET * 4;

  int kx1[2], ky1[2], kx2[2], ky2[2], kar[2];
  int k = 0;

  for (int i = 0; i < POOLN; ++i) {
    float sc = s_score[i];
    if (!(sc > 0.01f)) break;   // sorted desc: all remaining invalid too
    uint2 bx = s_box[i];
    int x1 = bx.x & 0xFFFF, y1 = bx.x >> 16;
    int x2 = bx.y & 0xFFFF, y2 = bx.y >> 16;
    int area = (x2 - x1) * (y2 - y1);

    bool sup = false;
#pragma unroll
    for (int sidx = 0; sidx < 2; ++sidx) {
      int slot = (sidx << 6) | lane;
      if (slot < k) {
        int xx1 = max(x1, kx1[sidx]), yy1 = max(y1, ky1[sidx]);
        int xx2 = min(x2, kx2[sidx]), yy2 = min(y2, ky2[sidx]);
        int iw = max(xx2 - xx1, 0), ih = max(yy2 - yy1, 0);
        int inter = iw * ih;
        float iou = (float)inter / (float)(area + kar[sidx] - inter);
        sup = sup || (iou > 0.6f);
      }
    }
    if (!__any(sup)) {
      if ((k & 63) == lane) {
        int hi = k >> 6;
        kx1[hi] = x1; ky1[hi] = y1; kx2[hi] = x2; ky2[hi] = y2; kar[hi] = area;
      }
      if (lane == 0) {
        out_s[k] = sc;
        out_c[k] = (float)(int)s_cls[i];
        out_b[k * 4 + 0] = (float)x1;
        out_b[k * 4 + 1] = (float)y1;
        out_b[k * 4 + 2] = (float)x2;
        out_b[k * 4 + 3] = (float)y2;
      }
      ++k;
      if (k == MAXDET) break;
    }
  }

  for (int s = k + lane; s < MAXDET; s += 64) {
    out_s[s] = -1.0f;
    out_c[s] = -1.0f;
    out_b[s * 4 + 0] = -1.0f;
    out_b[s * 4 + 1] = -1.0f;
    out_b[s * 4 + 2] = -1.0f;
    out_b[s * 4 + 3] = -1.0f;
  }
}

// ---------------- launcher ----------------
extern "C" void kernel_launch(void* const* d_in, const int* in_sizes, int n_in,
                              void* d_out, int out_size, void* d_ws, size_t ws_size,
                              hipStream_t stream) {
  Ptrs args;
  for (int i = 0; i < 20; ++i) args.p[i] = (const float*)d_in[i];

  char* ws = (char*)d_ws;
  uint4* dec = (uint4*)ws;                              // 5,586,944 B
  ws += (size_t)BATCH * NPOS * 16;
  unsigned long long* pool = (unsigned long long*)ws;   // 424,960 B
  ws += (size_t)BATCH * POOLN * 8;
  unsigned long long* gbuf = (unsigned long long*)ws;   // 1,007,616 B (16B-aligned)
  ws += (size_t)BATCH * CAPTOT * 8;
  unsigned* sbuf = (unsigned*)ws;                       // 16*21824*4 = 1,396,736 B
  ws += (size_t)BATCH * NPOS * 4;
  unsigned* ghist = (unsigned*)ws;                      // 48*4096*4 = 786,432 B
  ws += (size_t)BATCH * 3 * NBINS * 4;
  int* gcnt = (int*)ws;                                 // 192 B  (zeroed by decode)
  ws += 192;
  int* bcut = (int*)ws;                                 // 192 B  (written by cutoff)
  float* out = (float*)d_out;

  hipMemsetAsync(ghist, 0, (size_t)BATCH * 3 * NBINS * 4, stream);

  decode_kernel<<<BATCH * DEC_BPI, 256, 0, stream>>>(args, dec, gbuf, gcnt, sbuf);
  hist_kernel<<<BATCH * HIST_TPI, 256, 0, stream>>>(sbuf, ghist);
  cutoff_kernel<<<BATCH * 3, 256, 0, stream>>>(ghist, bcut);
  gather_kernel<<<BATCH * GATHER_BPI, 256, 0, stream>>>(sbuf, bcut, gbuf, gcnt);
  sort_kernel<<<BATCH * 4, 256, 0, stream>>>(gbuf, gcnt);
  pos_kernel<<<BATCH * POS_BPI, 256, 0, stream>>>(gbuf, gcnt, pool);
  nms_kernel<<<BATCH, 64, 0, stream>>>(dec, pool, out);
}

// Round 2
// 347.798 us; speedup vs baseline: 1.0801x; 1.0801x over previous
//
#include <hip/hip_runtime.h>
#include <stdint.h>

// ---------------- problem constants ----------------
#define BATCH 16
#define NCLS 80
#define NPOS 21824            // 16384+4096+1024+256+64
#define POOLN 3320            // 1000+1000+1000+256+64
#define MAXDET 100

// superset segment capacities (multiples of 8)
#define CAP0 4096
#define CAP1 2432
#define CAP2 1024
#define C34 320
#define CAP34 320
#define SEG1 (CAP0)                    // 4096
#define SEG2 (CAP0 + CAP1)             // 6528
#define SEG3 (CAP0 + CAP1 + CAP2)      // 7552
#define CAPTOT (SEG3 + CAP34)          // 7872

#define DEC_BPI 341                    // 21824/64 anchors-per-block blocks per image
#define GATHER_BPI 16                  // 16 x 1344 = 21504 anchors (levels 0..2)
#define GATHER_CHUNK 1344              // multiple of 64 -> wave-uniform level
#define POS_BPI 13                     // 13 x 256 = 3328 >= 3320 pool elements

#define NBINS 4096                     // digit = nsb >> 20 (12-bit key prefix)
#define HIST_TPI 11                    // hist tasks per image: 8(l0) + 2(l1) + 1(l2)

__device__ const int d_lvl_off[5] = {0, 16384, 20480, 21504, 21760};
__device__ const int d_lvl_hw[5]  = {16384, 4096, 1024, 256, 64};

struct Ptrs { const float* p[20]; };

__device__ __forceinline__ void map_lvl(int r, int& level, int& hw) {
  if      (r < 16384) { level = 0; hw = r; }
  else if (r < 20480) { level = 1; hw = r - 16384; }
  else if (r < 21504) { level = 2; hw = r - 20480; }
  else if (r < 21760) { level = 3; hw = r - 21504; }
  else                { level = 4; hw = r - 21760; }
}

// key = (nsb)<<32 | (level<<20) | hw with nsb = ~score_bits; ascending ==
// (score desc, level asc, idx asc). Unique per image; ~0ULL is a strictly-greater
// sentinel. digit = nsb >> 20 is a 12-bit key PREFIX -> {digit <= B} downward-closed.

// ---------------- kernel 1: decode (exact R6 structure, proven ~70 us) ----------------
__global__ __launch_bounds__(256) void decode_kernel(Ptrs args, uint4* __restrict__ dec,
                                                     unsigned long long* __restrict__ gbuf,
                                                     int* __restrict__ gcnt,
                                                     unsigned* __restrict__ sbuf) {
  int b  = blockIdx.x / DEC_BPI;
  int bb = blockIdx.x - b * DEC_BPI;
  int t = threadIdx.x;
  if (bb == 0 && t < 3) gcnt[b * 3 + t] = 0;

  int flat0 = bb * 64;                      // level boundaries are all multiples of 64
  int level, hw0;
  map_lvl(flat0, level, hw0);
  int HW = d_lvl_hw[level];
  int aoff = t >> 2, part = t & 3;
  int hw = hw0 + aoff;
  long abase = (long)b * HW + hw;

  const float* cls = args.p[level * 4 + 0];
  const float* reg = args.p[level * 4 + 1];
  const float* ctr = args.p[level * 4 + 2];
  const float* pos = args.p[level * 4 + 3];

  const float4* c4 = (const float4*)(cls + abase * NCLS) + part * 5;
  float4 v0 = c4[0], v1 = c4[1], v2 = c4[2], v3 = c4[3], v4 = c4[4];

  float m = -1e30f; int am = 0;
  int cb = part * 20;
#define CHK(val, j) if ((val) > m) { m = (val); am = cb + (j); }
  CHK(v0.x, 0)  CHK(v0.y, 1)  CHK(v0.z, 2)  CHK(v0.w, 3)
  CHK(v1.x, 4)  CHK(v1.y, 5)  CHK(v1.z, 6)  CHK(v1.w, 7)
  CHK(v2.x, 8)  CHK(v2.y, 9)  CHK(v2.z, 10) CHK(v2.w, 11)
  CHK(v3.x, 12) CHK(v3.y, 13) CHK(v3.z, 14) CHK(v3.w, 15)
  CHK(v4.x, 16) CHK(v4.y, 17) CHK(v4.z, 18) CHK(v4.w, 19)
#undef CHK
#pragma unroll
  for (int d = 1; d <= 2; d <<= 1) {
    float om = __shfl_xor(m, d, 64);
    int   oa = __shfl_xor(am, d, 64);
    if (om > m || (om == m && oa < am)) { m = om; am = oa; }
  }

  if (part == 0) {
    float4 rg = *(const float4*)(reg + abase * 4);
    float  ct = ctr[abase];
    float2 ps = ((const float2*)pos)[abase];

    float e0 = expf(rg.x), e1 = expf(rg.y), e2 = expf(rg.z), e3 = expf(rg.w);
    int x1 = (int)(ps.x - e0);   // C truncation == .astype(int32)
    int y1 = (int)(ps.y - e1);
    int x2 = (int)(ps.x + e2);
    int y2 = (int)(ps.y + e3);
    x1 = max(x1, 0); y1 = max(y1, 0);
    x2 = min(x2, 1023); y2 = min(y2, 1023);

    float sigm = 1.0f / (1.0f + expf(-m));
    float sigc = 1.0f / (1.0f + expf(-ct));
    float score = sqrtf(sigm * sigc);

    uint4 e;
    e.x = __float_as_uint(score);
    e.y = (unsigned)am;
    e.z = (unsigned)(x1 & 0xFFFF) | ((unsigned)y1 << 16);
    e.w = (unsigned)(x2 & 0xFFFF) | ((unsigned)y2 << 16);
    dec[b * NPOS + flat0 + aoff] = e;

    unsigned nsb = ~e.x;
    sbuf[b * NPOS + flat0 + aoff] = nsb;
    if (level >= 3) {    // deterministic slots for complete levels 3/4
      unsigned long long key =
          ((unsigned long long)nsb << 32) | (unsigned)((level << 20) | hw);
      gbuf[(size_t)b * CAPTOT + SEG3 + ((level == 3) ? hw : 256 + hw)] = key;
    }
  }
}

// ---------------- kernel 2: wide histogram (LDS-local, merge nonzero bins) ------
__global__ __launch_bounds__(256) void hist_kernel(const unsigned* __restrict__ sbuf,
                                                   unsigned* __restrict__ ghist) {
  __shared__ unsigned h[NBINS];
  int img = blockIdx.x / HIST_TPI, task = blockIdx.x % HIST_TPI;
  int level, start, n;
  if      (task < 8)  { level = 0; start = task * 2048;       n = 2048; }
  else if (task < 10) { level = 1; start = (task - 8) * 2048; n = 2048; }
  else                { level = 2; start = 0;                 n = 1024; }
  int tid = threadIdx.x;

  for (int i = tid; i < NBINS; i += 256) h[i] = 0;
  __syncthreads();
  const unsigned* base = sbuf + img * NPOS + d_lvl_off[level] + start;
  for (int i = tid; i < n; i += 256)
    atomicAdd(&h[base[i] >> 20], 1u);
  __syncthreads();
  unsigned* gh = ghist + (unsigned)(img * 3 + level) * NBINS;
  for (int i = tid; i < NBINS; i += 256) {
    unsigned v = h[i];
    if (v) atomicAdd(&gh[i], v);
  }
}

// ---------------- kernel 3: cutoff (parallel scan; proven R7 logic, 4096 bins) ----
__global__ __launch_bounds__(256) void cutoff_kernel(const unsigned* __restrict__ ghist,
                                                     int* __restrict__ bcut) {
  __shared__ unsigned wpart[4];
  __shared__ int shB;
  int img = blockIdx.x / 3, level = blockIdx.x % 3;
  const unsigned* h = ghist + (unsigned)(img * 3 + level) * NBINS;
  int tid = threadIdx.x, lane = tid & 63, wv = tid >> 6;

  unsigned hl[16];
  unsigned s = 0;
#pragma unroll
  for (int k = 0; k < 16; ++k) { hl[k] = h[16 * tid + k]; s += hl[k]; }
  unsigned incl = s;
  for (int d = 1; d < 64; d <<= 1) {
    unsigned v = __shfl_up(incl, d, 64);
    if (lane >= d) incl += v;
  }
  if (lane == 63) wpart[wv] = incl;
  __syncthreads();
  unsigned woff = 0;
  for (int w = 0; w < wv; ++w) woff += wpart[w];
  unsigned excl = woff + incl - s;
  if (excl < 1000u && excl + s >= 1000u) {       // unique crossing thread (N >= 1000)
    unsigned cum = excl; int B = NBINS - 1;
#pragma unroll
    for (int k = 0; k < 16; ++k) {
      cum += hl[k];
      if (cum >= 1000u) { B = 16 * tid + k; break; }
    }
    shB = B;
  }
  __syncthreads();
  if (tid == 0) bcut[img * 3 + level] = shB;
}

// ---------------- kernel 4: wide gather -> single gbuf layout (proven R7) ------
__global__ __launch_bounds__(256) void gather_kernel(const unsigned* __restrict__ sbuf,
                                                     const int* __restrict__ bcut,
                                                     unsigned long long* __restrict__ gbuf,
                                                     int* __restrict__ gcnt) {
  int img = blockIdx.x / GATHER_BPI, bb = blockIdx.x % GATHER_BPI;
  int tid = threadIdx.x, lane = tid & 63;
  int start = bb * GATHER_CHUNK;
  int b0 = bcut[img * 3 + 0], b1 = bcut[img * 3 + 1], b2 = bcut[img * 3 + 2];
  unsigned long long* gb = gbuf + (size_t)img * CAPTOT;

  for (int j = start + tid; j < start + GATHER_CHUNK; j += 256) {
    int level, hw;
    map_lvl(j, level, hw);                       // level wave-uniform (64-aligned groups)
    unsigned nsb = sbuf[img * NPOS + j];
    bool sel = (int)(nsb >> 20) <= ((level == 0) ? b0 : (level == 1) ? b1 : b2);
    unsigned long long msk = __ballot(sel);
    if (msk) {
      int nsel = __popcll(msk);
      int bas = 0;
      if (lane == 0) bas = atomicAdd(&gcnt[img * 3 + level], nsel);
      bas = __shfl(bas, 0, 64);
      if (sel) {
        int p = bas + __popcll(msk & ((1ULL << lane) - 1ULL));
        int cap   = (level == 0) ? CAP0 : (level == 1) ? CAP1 : CAP2;
        int sbase = (level == 0) ? 0    : (level == 1) ? SEG1 : SEG2;
        unsigned long long key =
            ((unsigned long long)nsb << 32) | (unsigned)((level << 20) | hw);
        if (p < cap) gb[sbase + p] = key;
      }
    }
  }
}

// ---------------- kernel 5a: register-blocked bitonic sort (V=16/thread) -------
// Same comparator / sentinel semantics as before, so the result is bit-identical;
// only the schedule changed. j<16 stages: in-register (no barriers). 16<=j<=512:
// __shfl_xor exchange (same wave, no barriers). j in {1024,2048}: LDS exchange
// (<=3 phases total). Network size adapts: Pnet = next pow2 >= c (>=512).
#define SWQ(q) ((q) ^ (((q) >> 3) & 7))          // pair-index XOR swizzle (bijective)

__device__ __forceinline__ void cmpswap(unsigned long long& a, unsigned long long& b,
                                        bool asc) {
  unsigned long long mn = a < b ? a : b;
  unsigned long long mx = a < b ? b : a;
  a = asc ? mn : mx;
  b = asc ? mx : mn;
}

__global__ __launch_bounds__(256) void sort_kernel(unsigned long long* __restrict__ gbuf,
                                                   const int* __restrict__ gcnt) {
  __shared__ ulonglong2 lds2[2048];              // 4096 u64 = 32 KiB
  int img = blockIdx.x >> 2, sg = blockIdx.x & 3;
  int t = threadIdx.x;
  unsigned long long* gb = gbuf + (size_t)img * CAPTOT;

  int base, cap;
  if      (sg == 0) { base = 0;    cap = CAP0; }
  else if (sg == 1) { base = SEG1; cap = CAP1; }
  else if (sg == 2) { base = SEG2; cap = CAP2; }
  else              { base = SEG3; cap = C34;  }
  int c = (sg < 3) ? min(gcnt[img * 3 + sg], cap) : C34;

  int Pnet = 512;
  while (Pnet < c) Pnet <<= 1;                   // <= 4096

  // ---- stage in: global -> LDS (coalesced, sentinel-padded) -> regs ----
  for (int q = t; q < (Pnet >> 1); q += 256) {
    int e0 = 2 * q;
    ulonglong2 val;
    val.x = (e0     < c) ? gb[base + e0]     : ~0ULL;
    val.y = (e0 + 1 < c) ? gb[base + e0 + 1] : ~0ULL;
    lds2[SWQ(q)] = val;
  }
  __syncthreads();

  unsigned long long key[16];
  if (t * 16 < Pnet) {
#pragma unroll
    for (int w = 0; w < 8; ++w) {
      ulonglong2 val = lds2[SWQ(t * 8 + w)];
      key[2 * w]     = val.x;
      key[2 * w + 1] = val.y;
    }
  } else {
#pragma unroll
    for (int v = 0; v < 16; ++v) key[v] = ~0ULL;
  }

  // ---- k = 2,4,8: fully in-register, compile-time directions ----
#pragma unroll
  for (int kk = 2; kk <= 8; kk <<= 1)
#pragma unroll
    for (int j = kk >> 1; j >= 1; j >>= 1)
#pragma unroll
      for (int v = 0; v < 16; ++v)
        if (!(v & j)) cmpswap(key[v], key[v | j], (v & kk) == 0);

  // ---- k = 16 .. Pnet ----
  for (int k = 16; k <= Pnet; k <<= 1) {
    bool asc = (t & (k >> 4)) == 0;              // dir of this thread's whole chunk
    for (int j = k >> 1; j >= 16; j >>= 1) {
      int d = j >> 4;                            // partner thread distance
      bool keep_min = ((t & d) == 0) == asc;
      if (d <= 32) {                             // same wave: shuffle exchange
#pragma unroll
        for (int v = 0; v < 16; ++v) {
          unsigned long long p = __shfl_xor(key[v], d, 64);
          unsigned long long mn = key[v] < p ? key[v] : p;
          unsigned long long mx = key[v] < p ? p : key[v];
          key[v] = keep_min ? mn : mx;
        }
      } else {                                   // cross-wave: LDS exchange
        __syncthreads();
#pragma unroll
        for (int w = 0; w < 8; ++w)
          lds2[SWQ(t * 8 + w)] = make_ulonglong2(key[2 * w], key[2 * w + 1]);
        __syncthreads();
        int tp = t ^ d;
#pragma unroll
        for (int w = 0; w < 8; ++w) {
          ulonglong2 pv = lds2[SWQ(tp * 8 + w)];
          unsigned long long a = key[2 * w], b = key[2 * w + 1];
          unsigned long long mn0 = a < pv.x ? a : pv.x, mx0 = a < pv.x ? pv.x : a;
          unsigned long long mn1 = b < pv.y ? b : pv.y, mx1 = b < pv.y ? pv.y : b;
          key[2 * w]     = keep_min ? mn0 : mx0;
          key[2 * w + 1] = keep_min ? mn1 : mx1;
        }
      }
    }
    // tail j = 8..1: in-register, uniform direction
#pragma unroll
    for (int j = 8; j >= 1; j >>= 1)
#pragma unroll
      for (int v = 0; v < 16; ++v)
        if (!(v & j)) cmpswap(key[v], key[v | j], asc);
  }

  // ---- stage out: regs -> LDS -> global (coalesced) ----
  __syncthreads();
  if (t * 16 < Pnet) {
#pragma unroll
    for (int w = 0; w < 8; ++w)
      lds2[SWQ(t * 8 + w)] = make_ulonglong2(key[2 * w], key[2 * w + 1]);
  }
  __syncthreads();
  int npairs = (c + 1) >> 1;                     // may write one sentinel pad (slot < cap, never read)
  ulonglong2* gb2 = (ulonglong2*)(gb + base);    // base is a multiple of 8 -> 16B aligned
  for (int q = t; q < npairs; q += 256) gb2[q] = lds2[SWQ(q)];
}

// ---------------- kernel 5b: position via binary search -> sorted pool --------
// One thread per pool element (t, i) with i < min(c_t,1000)  ==  old sel set
// (sorted index == old own-segment less-than count). pos = i + sum over other
// segments of min(lower_bound(seg, key), 1000)  ==  old sum of min(n_seg,1000).
__device__ __forceinline__ int lbound(const unsigned long long* __restrict__ a,
                                      int n, unsigned long long x) {
  int lo = 0, len = n;
  while (len > 0) {
    int half = len >> 1;
    int mid = lo + half;
    if (a[mid] < x) { lo = mid + 1; len -= half + 1; }
    else            { len = half; }
  }
  return lo;
}

__global__ __launch_bounds__(256) void pos_kernel(const unsigned long long* __restrict__ gbuf,
                                                  const int* __restrict__ gcnt,
                                                  unsigned long long* __restrict__ pool) {
  int img = blockIdx.x / POS_BPI, bb = blockIdx.x % POS_BPI;
  int e = bb * 256 + threadIdx.x;
  const unsigned long long* gb = gbuf + (size_t)img * CAPTOT;

  int c0 = min(gcnt[img * 3 + 0], CAP0);
  int c1 = min(gcnt[img * 3 + 1], CAP1);
  int c2 = min(gcnt[img * 3 + 2], CAP2);
  int m0 = min(c0, 1000), m1 = min(c1, 1000), m2 = min(c2, 1000);
  int tot = m0 + m1 + m2 + C34;
  if (e >= tot) return;

  int t, i;
  if      (e < m0)           { t = 0; i = e; }
  else if (e < m0 + m1)      { t = 1; i = e - m0; }
  else if (e < m0 + m1 + m2) { t = 2; i = e - m0 - m1; }
  else                       { t = 3; i = e - m0 - m1 - m2; }

  const int off[4] = {0, SEG1, SEG2, SEG3};
  const int cc[4]  = {c0, c1, c2, C34};

  unsigned long long key = gb[off[t] + i];
  int pos = i;                                   // own-segment term: min(rank,1000)=i
#pragma unroll
  for (int u = 0; u < 4; ++u) {
    if (u == t) continue;
    pos += min(lbound(gb + off[u], cc[u], key), 1000);
  }
  pool[img * POOLN + pos] = key;
}

// ---------------- kernel 6: per-image greedy NMS + output (bit-identical, proven) --
__global__ __launch_bounds__(64) void nms_kernel(const uint4* __restrict__ dec,
                                                 const unsigned long long* __restrict__ pool,
                                                 float* __restrict__ out) {
  __shared__ float          s_score[POOLN];
  __shared__ unsigned short s_cls[POOLN];
  __shared__ uint2          s_box[POOLN];
  int img = blockIdx.x;
  int lane = threadIdx.x;

  for (int r = lane; r < POOLN; r += 64) {
    unsigned long long key = pool[img * POOLN + r];
    unsigned low = (unsigned)key;
    int level = (low >> 20) & 7;
    int idx = low & 0xFFFFF;
    uint4 e = dec[img * NPOS + d_lvl_off[level] + idx];
    s_score[r] = __uint_as_float(e.x);
    s_cls[r]   = (unsigned short)e.y;
    s_box[r]   = make_uint2(e.z, e.w);
  }
  __syncthreads();

  float* out_s = out + img * MAXDET;
  float* out_c = out + BATCH * MAXDET + img * MAXDET;
  float* out_b = out + 2 * BATCH * MAXDET + img * MAXDET * 4;

  int kx1[2], ky1[2], kx2[2], ky2[2], kar[2];
  int k = 0;

  for (int i = 0; i < POOLN; ++i) {
    float sc = s_score[i];
    if (!(sc > 0.01f)) break;   // sorted desc: all remaining invalid too
    uint2 bx = s_box[i];
    int x1 = bx.x & 0xFFFF, y1 = bx.x >> 16;
    int x2 = bx.y & 0xFFFF, y2 = bx.y >> 16;
    int area = (x2 - x1) * (y2 - y1);

    bool sup = false;
#pragma unroll
    for (int sidx = 0; sidx < 2; ++sidx) {
      int slot = (sidx << 6) | lane;
      if (slot < k) {
        int xx1 = max(x1, kx1[sidx]), yy1 = max(y1, ky1[sidx]);
        int xx2 = min(x2, kx2[sidx]), yy2 = min(y2, ky2[sidx]);
        int iw = max(xx2 - xx1, 0), ih = max(yy2 - yy1, 0);
        int inter = iw * ih;
        float iou = (float)inter / (float)(area + kar[sidx] - inter);
        sup = sup || (iou > 0.6f);
      }
    }
    if (!__any(sup)) {
      if ((k & 63) == lane) {
        int hi = k >> 6;
        kx1[hi] = x1; ky1[hi] = y1; kx2[hi] = x2; ky2[hi] = y2; kar[hi] = area;
      }
      if (lane == 0) {
        out_s[k] = sc;
        out_c[k] = (float)(int)s_cls[i];
        out_b[k * 4 + 0] = (float)x1;
        out_b[k * 4 + 1] = (float)y1;
        out_b[k * 4 + 2] = (float)x2;
        out_b[k * 4 + 3] = (float)y2;
      }
      ++k;
      if (k == MAXDET) break;
    }
  }

  for (int s = k + lane; s < MAXDET; s += 64) {
    out_s[s] = -1.0f;
    out_c[s] = -1.0f;
    out_b[s * 4 + 0] = -1.0f;
    out_b[s * 4 + 1] = -1.0f;
    out_b[s * 4 + 2] = -1.0f;
    out_b[s * 4 + 3] = -1.0f;
  }
}

// ---------------- launcher ----------------
extern "C" void kernel_launch(void* const* d_in, const int* in_sizes, int n_in,
                              void* d_out, int out_size, void* d_ws, size_t ws_size,
                              hipStream_t stream) {
  Ptrs args;
  for (int i = 0; i < 20; ++i) args.p[i] = (const float*)d_in[i];

  char* ws = (char*)d_ws;
  uint4* dec = (uint4*)ws;                              // 5,586,944 B
  ws += (size_t)BATCH * NPOS * 16;
  unsigned long long* pool = (unsigned long long*)ws;   // 424,960 B
  ws += (size_t)BATCH * POOLN * 8;
  unsigned long long* gbuf = (unsigned long long*)ws;   // 1,007,616 B (16B-aligned)
  ws += (size_t)BATCH * CAPTOT * 8;
  unsigned* sbuf = (unsigned*)ws;                       // 16*21824*4 = 1,396,736 B
  ws += (size_t)BATCH * NPOS * 4;
  unsigned* ghist = (unsigned*)ws;                      // 48*4096*4 = 786,432 B
  ws += (size_t)BATCH * 3 * NBINS * 4;
  int* gcnt = (int*)ws;                                 // 192 B  (zeroed by decode)
  ws += 192;
  int* bcut = (int*)ws;                                 // 192 B  (written by cutoff)
  float* out = (float*)d_out;

  hipMemsetAsync(ghist, 0, (size_t)BATCH * 3 * NBINS * 4, stream);

  decode_kernel<<<BATCH * DEC_BPI, 256, 0, stream>>>(args, dec, gbuf, gcnt, sbuf);
  hist_kernel<<<BATCH * HIST_TPI, 256, 0, stream>>>(sbuf, ghist);
  cutoff_kernel<<<BATCH * 3, 256, 0, stream>>>(ghist, bcut);
  gather_kernel<<<BATCH * GATHER_BPI, 256, 0, stream>>>(sbuf, bcut, gbuf, gcnt);
  sort_kernel<<<BATCH * 4, 256, 0, stream>>>(gbuf, gcnt);
  pos_kernel<<<BATCH * POS_BPI, 256, 0, stream>>>(gbuf, gcnt, pool);
  nms_kernel<<<BATCH, 64, 0, stream>>>(dec, pool, out);
}

// Round 3
// 347.101 us; speedup vs baseline: 1.0823x; 1.0020x over previous
//
#include <hip/hip_runtime.h>
#include <stdint.h>

// ---------------- problem constants ----------------
#define BATCH 16
#define NCLS 80
#define NPOS 21824            // 16384+4096+1024+256+64
#define POOLN 3320            // 1000+1000+1000+256+64
#define MAXDET 100

// superset segment capacities (multiples of 8)
#define CAP0 4096
#define CAP1 2432
#define CAP2 1024
#define C34 320
#define CAP34 320
#define SEG1 (CAP0)                    // 4096
#define SEG2 (CAP0 + CAP1)             // 6528
#define SEG3 (CAP0 + CAP1 + CAP2)      // 7552
#define CAPTOT (SEG3 + CAP34)          // 7872

#define DEC_BPI 341                    // 21824/64 anchors-per-block blocks per image
#define GATHER_BPI 16                  // 16 x 1344 = 21504 anchors (levels 0..2)
#define GATHER_CHUNK 1344              // multiple of 64 -> wave-uniform level
#define POS_BPI 13                     // 13 x 256 = 3328 >= 3320 pool elements

#define NBINS 4096                     // digit = nsb >> 20 (12-bit key prefix)
#define HIST_TPI 11                    // hist tasks per image: 8(l0) + 2(l1) + 1(l2)

__device__ const int d_lvl_off[5] = {0, 16384, 20480, 21504, 21760};
__device__ const int d_lvl_hw[5]  = {16384, 4096, 1024, 256, 64};

struct Ptrs { const float* p[20]; };

__device__ __forceinline__ void map_lvl(int r, int& level, int& hw) {
  if      (r < 16384) { level = 0; hw = r; }
  else if (r < 20480) { level = 1; hw = r - 16384; }
  else if (r < 21504) { level = 2; hw = r - 20480; }
  else if (r < 21760) { level = 3; hw = r - 21504; }
  else                { level = 4; hw = r - 21760; }
}

// key = (nsb)<<32 | (level<<20) | hw with nsb = ~score_bits; ascending ==
// (score desc, level asc, idx asc). Unique per image; ~0ULL is a strictly-greater
// sentinel. digit = nsb >> 20 is a 12-bit key PREFIX -> {digit <= B} downward-closed.

// ---------------- kernel 1: decode (exact R6 structure, proven ~70 us) ----------------
__global__ __launch_bounds__(256) void decode_kernel(Ptrs args, uint4* __restrict__ dec,
                                                     unsigned long long* __restrict__ gbuf,
                                                     int* __restrict__ gcnt,
                                                     unsigned* __restrict__ sbuf) {
  int b  = blockIdx.x / DEC_BPI;
  int bb = blockIdx.x - b * DEC_BPI;
  int t = threadIdx.x;
  if (bb == 0 && t < 3) gcnt[b * 3 + t] = 0;

  int flat0 = bb * 64;                      // level boundaries are all multiples of 64
  int level, hw0;
  map_lvl(flat0, level, hw0);
  int HW = d_lvl_hw[level];
  int aoff = t >> 2, part = t & 3;
  int hw = hw0 + aoff;
  long abase = (long)b * HW + hw;

  const float* cls = args.p[level * 4 + 0];
  const float* reg = args.p[level * 4 + 1];
  const float* ctr = args.p[level * 4 + 2];
  const float* pos = args.p[level * 4 + 3];

  const float4* c4 = (const float4*)(cls + abase * NCLS) + part * 5;
  float4 v0 = c4[0], v1 = c4[1], v2 = c4[2], v3 = c4[3], v4 = c4[4];

  float m = -1e30f; int am = 0;
  int cb = part * 20;
#define CHK(val, j) if ((val) > m) { m = (val); am = cb + (j); }
  CHK(v0.x, 0)  CHK(v0.y, 1)  CHK(v0.z, 2)  CHK(v0.w, 3)
  CHK(v1.x, 4)  CHK(v1.y, 5)  CHK(v1.z, 6)  CHK(v1.w, 7)
  CHK(v2.x, 8)  CHK(v2.y, 9)  CHK(v2.z, 10) CHK(v2.w, 11)
  CHK(v3.x, 12) CHK(v3.y, 13) CHK(v3.z, 14) CHK(v3.w, 15)
  CHK(v4.x, 16) CHK(v4.y, 17) CHK(v4.z, 18) CHK(v4.w, 19)
#undef CHK
#pragma unroll
  for (int d = 1; d <= 2; d <<= 1) {
    float om = __shfl_xor(m, d, 64);
    int   oa = __shfl_xor(am, d, 64);
    if (om > m || (om == m && oa < am)) { m = om; am = oa; }
  }

  if (part == 0) {
    float4 rg = *(const float4*)(reg + abase * 4);
    float  ct = ctr[abase];
    float2 ps = ((const float2*)pos)[abase];

    float e0 = expf(rg.x), e1 = expf(rg.y), e2 = expf(rg.z), e3 = expf(rg.w);
    int x1 = (int)(ps.x - e0);   // C truncation == .astype(int32)
    int y1 = (int)(ps.y - e1);
    int x2 = (int)(ps.x + e2);
    int y2 = (int)(ps.y + e3);
    x1 = max(x1, 0); y1 = max(y1, 0);
    x2 = min(x2, 1023); y2 = min(y2, 1023);

    float sigm = 1.0f / (1.0f + expf(-m));
    float sigc = 1.0f / (1.0f + expf(-ct));
    float score = sqrtf(sigm * sigc);

    uint4 e;
    e.x = __float_as_uint(score);
    e.y = (unsigned)am;
    e.z = (unsigned)(x1 & 0xFFFF) | ((unsigned)y1 << 16);
    e.w = (unsigned)(x2 & 0xFFFF) | ((unsigned)y2 << 16);
    dec[b * NPOS + flat0 + aoff] = e;

    unsigned nsb = ~e.x;
    sbuf[b * NPOS + flat0 + aoff] = nsb;
    if (level >= 3) {    // deterministic slots for complete levels 3/4
      unsigned long long key =
          ((unsigned long long)nsb << 32) | (unsigned)((level << 20) | hw);
      gbuf[(size_t)b * CAPTOT + SEG3 + ((level == 3) ? hw : 256 + hw)] = key;
    }
  }
}

// ---------------- kernel 2: wide histogram (LDS-local, merge nonzero bins) ------
__global__ __launch_bounds__(256) void hist_kernel(const unsigned* __restrict__ sbuf,
                                                   unsigned* __restrict__ ghist) {
  __shared__ unsigned h[NBINS];
  int img = blockIdx.x / HIST_TPI, task = blockIdx.x % HIST_TPI;
  int level, start, n;
  if      (task < 8)  { level = 0; start = task * 2048;       n = 2048; }
  else if (task < 10) { level = 1; start = (task - 8) * 2048; n = 2048; }
  else                { level = 2; start = 0;                 n = 1024; }
  int tid = threadIdx.x;

  for (int i = tid; i < NBINS; i += 256) h[i] = 0;
  __syncthreads();
  const unsigned* base = sbuf + img * NPOS + d_lvl_off[level] + start;
  for (int i = tid; i < n; i += 256)
    atomicAdd(&h[base[i] >> 20], 1u);
  __syncthreads();
  unsigned* gh = ghist + (unsigned)(img * 3 + level) * NBINS;
  for (int i = tid; i < NBINS; i += 256) {
    unsigned v = h[i];
    if (v) atomicAdd(&gh[i], v);
  }
}

// ---------------- kernel 3: cutoff (parallel scan; proven R7 logic, 4096 bins) ----
__global__ __launch_bounds__(256) void cutoff_kernel(const unsigned* __restrict__ ghist,
                                                     int* __restrict__ bcut) {
  __shared__ unsigned wpart[4];
  __shared__ int shB;
  int img = blockIdx.x / 3, level = blockIdx.x % 3;
  const unsigned* h = ghist + (unsigned)(img * 3 + level) * NBINS;
  int tid = threadIdx.x, lane = tid & 63, wv = tid >> 6;

  unsigned hl[16];
  unsigned s = 0;
#pragma unroll
  for (int k = 0; k < 16; ++k) { hl[k] = h[16 * tid + k]; s += hl[k]; }
  unsigned incl = s;
  for (int d = 1; d < 64; d <<= 1) {
    unsigned v = __shfl_up(incl, d, 64);
    if (lane >= d) incl += v;
  }
  if (lane == 63) wpart[wv] = incl;
  __syncthreads();
  unsigned woff = 0;
  for (int w = 0; w < wv; ++w) woff += wpart[w];
  unsigned excl = woff + incl - s;
  if (excl < 1000u && excl + s >= 1000u) {       // unique crossing thread (N >= 1000)
    unsigned cum = excl; int B = NBINS - 1;
#pragma unroll
    for (int k = 0; k < 16; ++k) {
      cum += hl[k];
      if (cum >= 1000u) { B = 16 * tid + k; break; }
    }
    shB = B;
  }
  __syncthreads();
  if (tid == 0) bcut[img * 3 + level] = shB;
}

// ---------------- kernel 4: wide gather -> single gbuf layout (proven R7) ------
__global__ __launch_bounds__(256) void gather_kernel(const unsigned* __restrict__ sbuf,
                                                     const int* __restrict__ bcut,
                                                     unsigned long long* __restrict__ gbuf,
                                                     int* __restrict__ gcnt) {
  int img = blockIdx.x / GATHER_BPI, bb = blockIdx.x % GATHER_BPI;
  int tid = threadIdx.x, lane = tid & 63;
  int start = bb * GATHER_CHUNK;
  int b0 = bcut[img * 3 + 0], b1 = bcut[img * 3 + 1], b2 = bcut[img * 3 + 2];
  unsigned long long* gb = gbuf + (size_t)img * CAPTOT;

  for (int j = start + tid; j < start + GATHER_CHUNK; j += 256) {
    int level, hw;
    map_lvl(j, level, hw);                       // level wave-uniform (64-aligned groups)
    unsigned nsb = sbuf[img * NPOS + j];
    bool sel = (int)(nsb >> 20) <= ((level == 0) ? b0 : (level == 1) ? b1 : b2);
    unsigned long long msk = __ballot(sel);
    if (msk) {
      int nsel = __popcll(msk);
      int bas = 0;
      if (lane == 0) bas = atomicAdd(&gcnt[img * 3 + level], nsel);
      bas = __shfl(bas, 0, 64);
      if (sel) {
        int p = bas + __popcll(msk & ((1ULL << lane) - 1ULL));
        int cap   = (level == 0) ? CAP0 : (level == 1) ? CAP1 : CAP2;
        int sbase = (level == 0) ? 0    : (level == 1) ? SEG1 : SEG2;
        unsigned long long key =
            ((unsigned long long)nsb << 32) | (unsigned)((level << 20) | hw);
        if (p < cap) gb[sbase + p] = key;
      }
    }
  }
}

// ---------------- kernel 5a: register-blocked bitonic sort (V=16/thread) -------
// Same comparator / sentinel semantics as before, so the result is bit-identical;
// only the schedule changed. j<16 stages: in-register (no barriers). 16<=j<=512:
// __shfl_xor exchange (same wave, no barriers). j in {1024,2048}: LDS exchange
// (<=3 phases total). Network size adapts: Pnet = next pow2 >= c (>=512).
#define SWQ(q) ((q) ^ (((q) >> 3) & 7))          // pair-index XOR swizzle (bijective)

__device__ __forceinline__ void cmpswap(unsigned long long& a, unsigned long long& b,
                                        bool asc) {
  unsigned long long mn = a < b ? a : b;
  unsigned long long mx = a < b ? b : a;
  a = asc ? mn : mx;
  b = asc ? mx : mn;
}

__global__ __launch_bounds__(256) void sort_kernel(unsigned long long* __restrict__ gbuf,
                                                   const int* __restrict__ gcnt) {
  __shared__ ulonglong2 lds2[2048];              // 4096 u64 = 32 KiB
  int img = blockIdx.x >> 2, sg = blockIdx.x & 3;
  int t = threadIdx.x;
  unsigned long long* gb = gbuf + (size_t)img * CAPTOT;

  int base, cap;
  if      (sg == 0) { base = 0;    cap = CAP0; }
  else if (sg == 1) { base = SEG1; cap = CAP1; }
  else if (sg == 2) { base = SEG2; cap = CAP2; }
  else              { base = SEG3; cap = C34;  }
  int c = (sg < 3) ? min(gcnt[img * 3 + sg], cap) : C34;

  int Pnet = 512;
  while (Pnet < c) Pnet <<= 1;                   // <= 4096

  // ---- stage in: global -> LDS (coalesced, sentinel-padded) -> regs ----
  for (int q = t; q < (Pnet >> 1); q += 256) {
    int e0 = 2 * q;
    ulonglong2 val;
    val.x = (e0     < c) ? gb[base + e0]     : ~0ULL;
    val.y = (e0 + 1 < c) ? gb[base + e0 + 1] : ~0ULL;
    lds2[SWQ(q)] = val;
  }
  __syncthreads();

  unsigned long long key[16];
  if (t * 16 < Pnet) {
#pragma unroll
    for (int w = 0; w < 8; ++w) {
      ulonglong2 val = lds2[SWQ(t * 8 + w)];
      key[2 * w]     = val.x;
      key[2 * w + 1] = val.y;
    }
  } else {
#pragma unroll
    for (int v = 0; v < 16; ++v) key[v] = ~0ULL;
  }

  // ---- k = 2,4,8: fully in-register, compile-time directions ----
#pragma unroll
  for (int kk = 2; kk <= 8; kk <<= 1)
#pragma unroll
    for (int j = kk >> 1; j >= 1; j >>= 1)
#pragma unroll
      for (int v = 0; v < 16; ++v)
        if (!(v & j)) cmpswap(key[v], key[v | j], (v & kk) == 0);

  // ---- k = 16 .. Pnet ----
  for (int k = 16; k <= Pnet; k <<= 1) {
    bool asc = (t & (k >> 4)) == 0;              // dir of this thread's whole chunk
    for (int j = k >> 1; j >= 16; j >>= 1) {
      int d = j >> 4;                            // partner thread distance
      bool keep_min = ((t & d) == 0) == asc;
      if (d <= 32) {                             // same wave: shuffle exchange
#pragma unroll
        for (int v = 0; v < 16; ++v) {
          unsigned long long p = __shfl_xor(key[v], d, 64);
          unsigned long long mn = key[v] < p ? key[v] : p;
          unsigned long long mx = key[v] < p ? p : key[v];
          key[v] = keep_min ? mn : mx;
        }
      } else {                                   // cross-wave: LDS exchange
        __syncthreads();
#pragma unroll
        for (int w = 0; w < 8; ++w)
          lds2[SWQ(t * 8 + w)] = make_ulonglong2(key[2 * w], key[2 * w + 1]);
        __syncthreads();
        int tp = t ^ d;
#pragma unroll
        for (int w = 0; w < 8; ++w) {
          ulonglong2 pv = lds2[SWQ(tp * 8 + w)];
          unsigned long long a = key[2 * w], b = key[2 * w + 1];
          unsigned long long mn0 = a < pv.x ? a : pv.x, mx0 = a < pv.x ? pv.x : a;
          unsigned long long mn1 = b < pv.y ? b : pv.y, mx1 = b < pv.y ? pv.y : b;
          key[2 * w]     = keep_min ? mn0 : mx0;
          key[2 * w + 1] = keep_min ? mn1 : mx1;
        }
      }
    }
    // tail j = 8..1: in-register, uniform direction
#pragma unroll
    for (int j = 8; j >= 1; j >>= 1)
#pragma unroll
      for (int v = 0; v < 16; ++v)
        if (!(v & j)) cmpswap(key[v], key[v | j], asc);
  }

  // ---- stage out: regs -> LDS -> global (coalesced) ----
  __syncthreads();
  if (t * 16 < Pnet) {
#pragma unroll
    for (int w = 0; w < 8; ++w)
      lds2[SWQ(t * 8 + w)] = make_ulonglong2(key[2 * w], key[2 * w + 1]);
  }
  __syncthreads();
  int npairs = (c + 1) >> 1;                     // may write one sentinel pad (slot < cap, never read)
  ulonglong2* gb2 = (ulonglong2*)(gb + base);    // base is a multiple of 8 -> 16B aligned
  for (int q = t; q < npairs; q += 256) gb2[q] = lds2[SWQ(q)];
}

// ---------------- kernel 5b: position via binary search -> sorted pool --------
__device__ __forceinline__ int lbound(const unsigned long long* __restrict__ a,
                                      int n, unsigned long long x) {
  int lo = 0, len = n;
  while (len > 0) {
    int half = len >> 1;
    int mid = lo + half;
    if (a[mid] < x) { lo = mid + 1; len -= half + 1; }
    else            { len = half; }
  }
  return lo;
}

__global__ __launch_bounds__(256) void pos_kernel(const unsigned long long* __restrict__ gbuf,
                                                  const int* __restrict__ gcnt,
                                                  unsigned long long* __restrict__ pool) {
  int img = blockIdx.x / POS_BPI, bb = blockIdx.x % POS_BPI;
  int e = bb * 256 + threadIdx.x;
  const unsigned long long* gb = gbuf + (size_t)img * CAPTOT;

  int c0 = min(gcnt[img * 3 + 0], CAP0);
  int c1 = min(gcnt[img * 3 + 1], CAP1);
  int c2 = min(gcnt[img * 3 + 2], CAP2);
  int m0 = min(c0, 1000), m1 = min(c1, 1000), m2 = min(c2, 1000);
  int tot = m0 + m1 + m2 + C34;
  if (e >= tot) return;

  int t, i;
  if      (e < m0)           { t = 0; i = e; }
  else if (e < m0 + m1)      { t = 1; i = e - m0; }
  else if (e < m0 + m1 + m2) { t = 2; i = e - m0 - m1; }
  else                       { t = 3; i = e - m0 - m1 - m2; }

  const int off[4] = {0, SEG1, SEG2, SEG3};
  const int cc[4]  = {c0, c1, c2, C34};

  unsigned long long key = gb[off[t] + i];
  int pos = i;                                   // own-segment term: min(rank,1000)=i
#pragma unroll
  for (int u = 0; u < 4; ++u) {
    if (u == t) continue;
    pos += min(lbound(gb + off[u], cc[u], key), 1000);
  }
  pool[img * POOLN + pos] = key;
}

// ---------------- kernel 6: per-image greedy NMS + output ----------------------
// Bit-identical decisions, leaner serial loop:
//  * candidates staged UNPACKED in LDS: int4 box + (score, area) pair
//  * one-iteration software prefetch of the next candidate (LDS latency hidden)
//  * division-free EXACT iou>0.6f test: fl(inter/union) > 0.6f  <=>
//      inter * 2^25 > 20132661 * union   (operands are exact integers; boundary
//      m = 20132661/2^25 is the round-nearest-even midpoint, tie -> 0.6f itself,
//      NaN case union=0 -> 0>0 false matches NaN>0.6f false)
//  * second kept-slot block skipped via wave-uniform branch while k <= 64
__global__ __launch_bounds__(64) void nms_kernel(const uint4* __restrict__ dec,
                                                 const unsigned long long* __restrict__ pool,
                                                 float* __restrict__ out) {
  __shared__ int4           s_box[POOLN];        // x1,y1,x2,y2 (ints)
  __shared__ float2         s_sa[POOLN];         // score, area-bits
  __shared__ unsigned short s_cls[POOLN];
  int img = blockIdx.x;
  int lane = threadIdx.x;

  for (int r = lane; r < POOLN; r += 64) {
    unsigned long long key = pool[img * POOLN + r];
    unsigned low = (unsigned)key;
    int level = (low >> 20) & 7;
    int idx = low & 0xFFFFF;
    uint4 e = dec[img * NPOS + d_lvl_off[level] + idx];
    int x1 = (int)(e.z & 0xFFFF), y1 = (int)(e.z >> 16);
    int x2 = (int)(e.w & 0xFFFF), y2 = (int)(e.w >> 16);
    s_box[r] = make_int4(x1, y1, x2, y2);
    s_sa[r]  = make_float2(__uint_as_float(e.x),
                           __int_as_float((x2 - x1) * (y2 - y1)));
    s_cls[r] = (unsigned short)e.y;
  }
  __syncthreads();

  float* out_s = out + img * MAXDET;
  float* out_c = out + BATCH * MAXDET + img * MAXDET;
  float* out_b = out + 2 * BATCH * MAXDET + img * MAXDET * 4;

  int kx1[2], ky1[2], kx2[2], ky2[2], kar[2];
  int k = 0;

  int4   bx_n = s_box[0];
  float2 sa_n = s_sa[0];

  for (int i = 0; i < POOLN; ++i) {
    int4  bx = bx_n;
    float sc = sa_n.x;
    int   ar = __float_as_int(sa_n.y);
    int ip = (i + 1 < POOLN) ? i + 1 : i;        // prefetch next candidate early
    bx_n = s_box[ip];
    sa_n = s_sa[ip];

    if (!(sc > 0.01f)) break;   // sorted desc: all remaining invalid too

    bool sup = false;
    if (lane < k) {              // kept slot 0..63
      int xx1 = max(bx.x, kx1[0]), yy1 = max(bx.y, ky1[0]);
      int xx2 = min(bx.z, kx2[0]), yy2 = min(bx.w, ky2[0]);
      int iw = max(xx2 - xx1, 0), ih = max(yy2 - yy1, 0);
      int inter = iw * ih;
      int uni = ar + kar[0] - inter;
      sup = ((long long)inter << 25) > 20132661LL * (long long)uni;
    }
    if (k > 64) {                // kept slot 64..99 (wave-uniform skip)
      if (64 + lane < k) {
        int xx1 = max(bx.x, kx1[1]), yy1 = max(bx.y, ky1[1]);
        int xx2 = min(bx.z, kx2[1]), yy2 = min(bx.w, ky2[1]);
        int iw = max(xx2 - xx1, 0), ih = max(yy2 - yy1, 0);
        int inter = iw * ih;
        int uni = ar + kar[1] - inter;
        sup = sup || (((long long)inter << 25) > 20132661LL * (long long)uni);
      }
    }

    if (!__any(sup)) {
      if ((k & 63) == lane) {
        int hi = k >> 6;
        kx1[hi] = bx.x; ky1[hi] = bx.y; kx2[hi] = bx.z; ky2[hi] = bx.w; kar[hi] = ar;
      }
      if (lane == 0) {
        out_s[k] = sc;
        out_c[k] = (float)(int)s_cls[i];
        out_b[k * 4 + 0] = (float)bx.x;
        out_b[k * 4 + 1] = (float)bx.y;
        out_b[k * 4 + 2] = (float)bx.z;
        out_b[k * 4 + 3] = (float)bx.w;
      }
      ++k;
      if (k == MAXDET) break;
    }
  }

  for (int s = k + lane; s < MAXDET; s += 64) {
    out_s[s] = -1.0f;
    out_c[s] = -1.0f;
    out_b[s * 4 + 0] = -1.0f;
    out_b[s * 4 + 1] = -1.0f;
    out_b[s * 4 + 2] = -1.0f;
    out_b[s * 4 + 3] = -1.0f;
  }
}

// ---------------- launcher ----------------
extern "C" void kernel_launch(void* const* d_in, const int* in_sizes, int n_in,
                              void* d_out, int out_size, void* d_ws, size_t ws_size,
                              hipStream_t stream) {
  Ptrs args;
  for (int i = 0; i < 20; ++i) args.p[i] = (const float*)d_in[i];

  char* ws = (char*)d_ws;
  uint4* dec = (uint4*)ws;                              // 5,586,944 B
  ws += (size_t)BATCH * NPOS * 16;
  unsigned long long* pool = (unsigned long long*)ws;   // 424,960 B
  ws += (size_t)BATCH * POOLN * 8;
  unsigned long long* gbuf = (unsigned long long*)ws;   // 1,007,616 B (16B-aligned)
  ws += (size_t)BATCH * CAPTOT * 8;
  unsigned* sbuf = (unsigned*)ws;                       // 16*21824*4 = 1,396,736 B
  ws += (size_t)BATCH * NPOS * 4;
  unsigned* ghist = (unsigned*)ws;                      // 48*4096*4 = 786,432 B
  ws += (size_t)BATCH * 3 * NBINS * 4;
  int* gcnt = (int*)ws;                                 // 192 B  (zeroed by decode)
  ws += 192;
  int* bcut = (int*)ws;                                 // 192 B  (written by cutoff)
  float* out = (float*)d_out;

  hipMemsetAsync(ghist, 0, (size_t)BATCH * 3 * NBINS * 4, stream);

  decode_kernel<<<BATCH * DEC_BPI, 256, 0, stream>>>(args, dec, gbuf, gcnt, sbuf);
  hist_kernel<<<BATCH * HIST_TPI, 256, 0, stream>>>(sbuf, ghist);
  cutoff_kernel<<<BATCH * 3, 256, 0, stream>>>(ghist, bcut);
  gather_kernel<<<BATCH * GATHER_BPI, 256, 0, stream>>>(sbuf, bcut, gbuf, gcnt);
  sort_kernel<<<BATCH * 4, 256, 0, stream>>>(gbuf, gcnt);
  pos_kernel<<<BATCH * POS_BPI, 256, 0, stream>>>(gbuf, gcnt, pool);
  nms_kernel<<<BATCH, 64, 0, stream>>>(dec, pool, out);
}

// Round 4
// 310.188 us; speedup vs baseline: 1.2111x; 1.1190x over previous
//
#include <hip/hip_runtime.h>
#include <stdint.h>

// ---------------- problem constants ----------------
#define BATCH 16
#define NCLS 80
#define NPOS 21824            // 16384+4096+1024+256+64
#define POOLN 3320            // 1000+1000+1000+256+64
#define MAXDET 100

// superset segment capacities (multiples of 8)
#define CAP0 4096
#define CAP1 2432
#define CAP2 1024
#define C34 320
#define CAP34 320
#define SEG1 (CAP0)                    // 4096
#define SEG2 (CAP0 + CAP1)             // 6528
#define SEG3 (CAP0 + CAP1 + CAP2)      // 7552
#define CAPTOT (SEG3 + CAP34)          // 7872

#define DEC_BPI 341                    // 21824/64 anchors-per-block blocks per image
#define GATHER_BPI 16                  // 16 x 1344 = 21504 anchors (levels 0..2)
#define GATHER_CHUNK 1344              // multiple of 64 -> wave-uniform level
#define POS_BPI 13                     // 13 x 256 = 3328 >= 3320 pool elements

#define NBINS 4096                     // digit = nsb >> 20 (12-bit key prefix)
#define HIST_TPI 11                    // hist tasks per image: 8(l0) + 2(l1) + 1(l2)

__device__ const int d_lvl_off[5] = {0, 16384, 20480, 21504, 21760};
__device__ const int d_lvl_hw[5]  = {16384, 4096, 1024, 256, 64};

struct Ptrs { const float* p[20]; };

__device__ __forceinline__ void map_lvl(int r, int& level, int& hw) {
  if      (r < 16384) { level = 0; hw = r; }
  else if (r < 20480) { level = 1; hw = r - 16384; }
  else if (r < 21504) { level = 2; hw = r - 20480; }
  else if (r < 21760) { level = 3; hw = r - 21504; }
  else                { level = 4; hw = r - 21760; }
}

// key = (nsb)<<32 | (level<<20) | hw with nsb = ~score_bits; ascending ==
// (score desc, level asc, idx asc). Unique per image; ~0ULL is a strictly-greater
// sentinel. digit = nsb >> 20 is a 12-bit key PREFIX -> {digit <= B} downward-closed.

// ---------------- kernel 1: decode (exact R6 structure, proven ~70 us) ----------------
__global__ __launch_bounds__(256) void decode_kernel(Ptrs args, uint4* __restrict__ dec,
                                                     unsigned long long* __restrict__ gbuf,
                                                     int* __restrict__ gcnt,
                                                     unsigned* __restrict__ sbuf) {
  int b  = blockIdx.x / DEC_BPI;
  int bb = blockIdx.x - b * DEC_BPI;
  int t = threadIdx.x;
  if (bb == 0 && t < 3) gcnt[b * 3 + t] = 0;

  int flat0 = bb * 64;                      // level boundaries are all multiples of 64
  int level, hw0;
  map_lvl(flat0, level, hw0);
  int HW = d_lvl_hw[level];
  int aoff = t >> 2, part = t & 3;
  int hw = hw0 + aoff;
  long abase = (long)b * HW + hw;

  const float* cls = args.p[level * 4 + 0];
  const float* reg = args.p[level * 4 + 1];
  const float* ctr = args.p[level * 4 + 2];
  const float* pos = args.p[level * 4 + 3];

  const float4* c4 = (const float4*)(cls + abase * NCLS) + part * 5;
  float4 v0 = c4[0], v1 = c4[1], v2 = c4[2], v3 = c4[3], v4 = c4[4];

  float m = -1e30f; int am = 0;
  int cb = part * 20;
#define CHK(val, j) if ((val) > m) { m = (val); am = cb + (j); }
  CHK(v0.x, 0)  CHK(v0.y, 1)  CHK(v0.z, 2)  CHK(v0.w, 3)
  CHK(v1.x, 4)  CHK(v1.y, 5)  CHK(v1.z, 6)  CHK(v1.w, 7)
  CHK(v2.x, 8)  CHK(v2.y, 9)  CHK(v2.z, 10) CHK(v2.w, 11)
  CHK(v3.x, 12) CHK(v3.y, 13) CHK(v3.z, 14) CHK(v3.w, 15)
  CHK(v4.x, 16) CHK(v4.y, 17) CHK(v4.z, 18) CHK(v4.w, 19)
#undef CHK
#pragma unroll
  for (int d = 1; d <= 2; d <<= 1) {
    float om = __shfl_xor(m, d, 64);
    int   oa = __shfl_xor(am, d, 64);
    if (om > m || (om == m && oa < am)) { m = om; am = oa; }
  }

  if (part == 0) {
    float4 rg = *(const float4*)(reg + abase * 4);
    float  ct = ctr[abase];
    float2 ps = ((const float2*)pos)[abase];

    float e0 = expf(rg.x), e1 = expf(rg.y), e2 = expf(rg.z), e3 = expf(rg.w);
    int x1 = (int)(ps.x - e0);   // C truncation == .astype(int32)
    int y1 = (int)(ps.y - e1);
    int x2 = (int)(ps.x + e2);
    int y2 = (int)(ps.y + e3);
    x1 = max(x1, 0); y1 = max(y1, 0);
    x2 = min(x2, 1023); y2 = min(y2, 1023);

    float sigm = 1.0f / (1.0f + expf(-m));
    float sigc = 1.0f / (1.0f + expf(-ct));
    float score = sqrtf(sigm * sigc);

    uint4 e;
    e.x = __float_as_uint(score);
    e.y = (unsigned)am;
    e.z = (unsigned)(x1 & 0xFFFF) | ((unsigned)y1 << 16);
    e.w = (unsigned)(x2 & 0xFFFF) | ((unsigned)y2 << 16);
    dec[b * NPOS + flat0 + aoff] = e;

    unsigned nsb = ~e.x;
    sbuf[b * NPOS + flat0 + aoff] = nsb;
    if (level >= 3) {    // deterministic slots for complete levels 3/4
      unsigned long long key =
          ((unsigned long long)nsb << 32) | (unsigned)((level << 20) | hw);
      gbuf[(size_t)b * CAPTOT + SEG3 + ((level == 3) ? hw : 256 + hw)] = key;
    }
  }
}

// ---------------- kernel 2: wide histogram (LDS-local, merge nonzero bins) ------
__global__ __launch_bounds__(256) void hist_kernel(const unsigned* __restrict__ sbuf,
                                                   unsigned* __restrict__ ghist) {
  __shared__ unsigned h[NBINS];
  int img = blockIdx.x / HIST_TPI, task = blockIdx.x % HIST_TPI;
  int level, start, n;
  if      (task < 8)  { level = 0; start = task * 2048;       n = 2048; }
  else if (task < 10) { level = 1; start = (task - 8) * 2048; n = 2048; }
  else                { level = 2; start = 0;                 n = 1024; }
  int tid = threadIdx.x;

  for (int i = tid; i < NBINS; i += 256) h[i] = 0;
  __syncthreads();
  const unsigned* base = sbuf + img * NPOS + d_lvl_off[level] + start;
  for (int i = tid; i < n; i += 256)
    atomicAdd(&h[base[i] >> 20], 1u);
  __syncthreads();
  unsigned* gh = ghist + (unsigned)(img * 3 + level) * NBINS;
  for (int i = tid; i < NBINS; i += 256) {
    unsigned v = h[i];
    if (v) atomicAdd(&gh[i], v);
  }
}

// ---------------- kernel 3: cutoff (parallel scan; proven R7 logic, 4096 bins) ----
__global__ __launch_bounds__(256) void cutoff_kernel(const unsigned* __restrict__ ghist,
                                                     int* __restrict__ bcut) {
  __shared__ unsigned wpart[4];
  __shared__ int shB;
  int img = blockIdx.x / 3, level = blockIdx.x % 3;
  const unsigned* h = ghist + (unsigned)(img * 3 + level) * NBINS;
  int tid = threadIdx.x, lane = tid & 63, wv = tid >> 6;

  unsigned hl[16];
  unsigned s = 0;
#pragma unroll
  for (int k = 0; k < 16; ++k) { hl[k] = h[16 * tid + k]; s += hl[k]; }
  unsigned incl = s;
  for (int d = 1; d < 64; d <<= 1) {
    unsigned v = __shfl_up(incl, d, 64);
    if (lane >= d) incl += v;
  }
  if (lane == 63) wpart[wv] = incl;
  __syncthreads();
  unsigned woff = 0;
  for (int w = 0; w < wv; ++w) woff += wpart[w];
  unsigned excl = woff + incl - s;
  if (excl < 1000u && excl + s >= 1000u) {       // unique crossing thread (N >= 1000)
    unsigned cum = excl; int B = NBINS - 1;
#pragma unroll
    for (int k = 0; k < 16; ++k) {
      cum += hl[k];
      if (cum >= 1000u) { B = 16 * tid + k; break; }
    }
    shB = B;
  }
  __syncthreads();
  if (tid == 0) bcut[img * 3 + level] = shB;
}

// ---------------- kernel 4: wide gather -> single gbuf layout (proven R7) ------
__global__ __launch_bounds__(256) void gather_kernel(const unsigned* __restrict__ sbuf,
                                                     const int* __restrict__ bcut,
                                                     unsigned long long* __restrict__ gbuf,
                                                     int* __restrict__ gcnt) {
  int img = blockIdx.x / GATHER_BPI, bb = blockIdx.x % GATHER_BPI;
  int tid = threadIdx.x, lane = tid & 63;
  int start = bb * GATHER_CHUNK;
  int b0 = bcut[img * 3 + 0], b1 = bcut[img * 3 + 1], b2 = bcut[img * 3 + 2];
  unsigned long long* gb = gbuf + (size_t)img * CAPTOT;

  for (int j = start + tid; j < start + GATHER_CHUNK; j += 256) {
    int level, hw;
    map_lvl(j, level, hw);                       // level wave-uniform (64-aligned groups)
    unsigned nsb = sbuf[img * NPOS + j];
    bool sel = (int)(nsb >> 20) <= ((level == 0) ? b0 : (level == 1) ? b1 : b2);
    unsigned long long msk = __ballot(sel);
    if (msk) {
      int nsel = __popcll(msk);
      int bas = 0;
      if (lane == 0) bas = atomicAdd(&gcnt[img * 3 + level], nsel);
      bas = __shfl(bas, 0, 64);
      if (sel) {
        int p = bas + __popcll(msk & ((1ULL << lane) - 1ULL));
        int cap   = (level == 0) ? CAP0 : (level == 1) ? CAP1 : CAP2;
        int sbase = (level == 0) ? 0    : (level == 1) ? SEG1 : SEG2;
        unsigned long long key =
            ((unsigned long long)nsb << 32) | (unsigned)((level << 20) | hw);
        if (p < cap) gb[sbase + p] = key;
      }
    }
  }
}

// ---------------- kernel 5a: register-blocked bitonic sort (V=16/thread) -------
// Same comparator / sentinel semantics as before, so the result is bit-identical;
// only the schedule changed. j<16 stages: in-register (no barriers). 16<=j<=512:
// __shfl_xor exchange (same wave, no barriers). j in {1024,2048}: LDS exchange
// (<=3 phases total). Network size adapts: Pnet = next pow2 >= c (>=512).
#define SWQ(q) ((q) ^ (((q) >> 3) & 7))          // pair-index XOR swizzle (bijective)

__device__ __forceinline__ void cmpswap(unsigned long long& a, unsigned long long& b,
                                        bool asc) {
  unsigned long long mn = a < b ? a : b;
  unsigned long long mx = a < b ? b : a;
  a = asc ? mn : mx;
  b = asc ? mx : mn;
}

__global__ __launch_bounds__(256) void sort_kernel(unsigned long long* __restrict__ gbuf,
                                                   const int* __restrict__ gcnt) {
  __shared__ ulonglong2 lds2[2048];              // 4096 u64 = 32 KiB
  int img = blockIdx.x >> 2, sg = blockIdx.x & 3;
  int t = threadIdx.x;
  unsigned long long* gb = gbuf + (size_t)img * CAPTOT;

  int base, cap;
  if      (sg == 0) { base = 0;    cap = CAP0; }
  else if (sg == 1) { base = SEG1; cap = CAP1; }
  else if (sg == 2) { base = SEG2; cap = CAP2; }
  else              { base = SEG3; cap = C34;  }
  int c = (sg < 3) ? min(gcnt[img * 3 + sg], cap) : C34;

  int Pnet = 512;
  while (Pnet < c) Pnet <<= 1;                   // <= 4096

  // ---- stage in: global -> LDS (coalesced, sentinel-padded) -> regs ----
  for (int q = t; q < (Pnet >> 1); q += 256) {
    int e0 = 2 * q;
    ulonglong2 val;
    val.x = (e0     < c) ? gb[base + e0]     : ~0ULL;
    val.y = (e0 + 1 < c) ? gb[base + e0 + 1] : ~0ULL;
    lds2[SWQ(q)] = val;
  }
  __syncthreads();

  unsigned long long key[16];
  if (t * 16 < Pnet) {
#pragma unroll
    for (int w = 0; w < 8; ++w) {
      ulonglong2 val = lds2[SWQ(t * 8 + w)];
      key[2 * w]     = val.x;
      key[2 * w + 1] = val.y;
    }
  } else {
#pragma unroll
    for (int v = 0; v < 16; ++v) key[v] = ~0ULL;
  }

  // ---- k = 2,4,8: fully in-register, compile-time directions ----
#pragma unroll
  for (int kk = 2; kk <= 8; kk <<= 1)
#pragma unroll
    for (int j = kk >> 1; j >= 1; j >>= 1)
#pragma unroll
      for (int v = 0; v < 16; ++v)
        if (!(v & j)) cmpswap(key[v], key[v | j], (v & kk) == 0);

  // ---- k = 16 .. Pnet ----
  for (int k = 16; k <= Pnet; k <<= 1) {
    bool asc = (t & (k >> 4)) == 0;              // dir of this thread's whole chunk
    for (int j = k >> 1; j >= 16; j >>= 1) {
      int d = j >> 4;                            // partner thread distance
      bool keep_min = ((t & d) == 0) == asc;
      if (d <= 32) {                             // same wave: shuffle exchange
#pragma unroll
        for (int v = 0; v < 16; ++v) {
          unsigned long long p = __shfl_xor(key[v], d, 64);
          unsigned long long mn = key[v] < p ? key[v] : p;
          unsigned long long mx = key[v] < p ? p : key[v];
          key[v] = keep_min ? mn : mx;
        }
      } else {                                   // cross-wave: LDS exchange
        __syncthreads();
#pragma unroll
        for (int w = 0; w < 8; ++w)
          lds2[SWQ(t * 8 + w)] = make_ulonglong2(key[2 * w], key[2 * w + 1]);
        __syncthreads();
        int tp = t ^ d;
#pragma unroll
        for (int w = 0; w < 8; ++w) {
          ulonglong2 pv = lds2[SWQ(tp * 8 + w)];
          unsigned long long a = key[2 * w], b = key[2 * w + 1];
          unsigned long long mn0 = a < pv.x ? a : pv.x, mx0 = a < pv.x ? pv.x : a;
          unsigned long long mn1 = b < pv.y ? b : pv.y, mx1 = b < pv.y ? pv.y : b;
          key[2 * w]     = keep_min ? mn0 : mx0;
          key[2 * w + 1] = keep_min ? mn1 : mx1;
        }
      }
    }
    // tail j = 8..1: in-register, uniform direction
#pragma unroll
    for (int j = 8; j >= 1; j >>= 1)
#pragma unroll
      for (int v = 0; v < 16; ++v)
        if (!(v & j)) cmpswap(key[v], key[v | j], asc);
  }

  // ---- stage out: regs -> LDS -> global (coalesced) ----
  __syncthreads();
  if (t * 16 < Pnet) {
#pragma unroll
    for (int w = 0; w < 8; ++w)
      lds2[SWQ(t * 8 + w)] = make_ulonglong2(key[2 * w], key[2 * w + 1]);
  }
  __syncthreads();
  int npairs = (c + 1) >> 1;                     // may write one sentinel pad (slot < cap, never read)
  ulonglong2* gb2 = (ulonglong2*)(gb + base);    // base is a multiple of 8 -> 16B aligned
  for (int q = t; q < npairs; q += 256) gb2[q] = lds2[SWQ(q)];
}

// ---------------- kernel 5b: position via binary search -> sorted pool --------
__device__ __forceinline__ int lbound(const unsigned long long* __restrict__ a,
                                      int n, unsigned long long x) {
  int lo = 0, len = n;
  while (len > 0) {
    int half = len >> 1;
    int mid = lo + half;
    if (a[mid] < x) { lo = mid + 1; len -= half + 1; }
    else            { len = half; }
  }
  return lo;
}

__global__ __launch_bounds__(256) void pos_kernel(const unsigned long long* __restrict__ gbuf,
                                                  const int* __restrict__ gcnt,
                                                  unsigned long long* __restrict__ pool) {
  int img = blockIdx.x / POS_BPI, bb = blockIdx.x % POS_BPI;
  int e = bb * 256 + threadIdx.x;
  const unsigned long long* gb = gbuf + (size_t)img * CAPTOT;

  int c0 = min(gcnt[img * 3 + 0], CAP0);
  int c1 = min(gcnt[img * 3 + 1], CAP1);
  int c2 = min(gcnt[img * 3 + 2], CAP2);
  int m0 = min(c0, 1000), m1 = min(c1, 1000), m2 = min(c2, 1000);
  int tot = m0 + m1 + m2 + C34;
  if (e >= tot) return;

  int t, i;
  if      (e < m0)           { t = 0; i = e; }
  else if (e < m0 + m1)      { t = 1; i = e - m0; }
  else if (e < m0 + m1 + m2) { t = 2; i = e - m0 - m1; }
  else                       { t = 3; i = e - m0 - m1 - m2; }

  const int off[4] = {0, SEG1, SEG2, SEG3};
  const int cc[4]  = {c0, c1, c2, C34};

  unsigned long long key = gb[off[t] + i];
  int pos = i;                                   // own-segment term: min(rank,1000)=i
#pragma unroll
  for (int u = 0; u < 4; ++u) {
    if (u == t) continue;
    pos += min(lbound(gb + off[u], cc[u], key), 1000);
  }
  pool[img * POOLN + pos] = key;
}

// ---------------- kernel 6: per-image greedy NMS, 64-wide batched --------------
// Exact greedy semantics, restructured for parallelism:
//  * batch of 64 candidates, one per lane, loaded pool->dec->REGISTERS directly
//    (no LDS staging phase at all)
//  * each lane tests its candidate vs ALL kept boxes (uniform LDS broadcast loop,
//    no serial dependence -> pipelines)
//  * in-batch resolve in ffs order: j = lowest unsuppressed lane is KEPT (its
//    fate is final: every earlier candidate was already resolved), broadcast its
//    box via __shfl, lanes > j apply the exact integer IoU test
//  * invalid (score<=0.01) candidates are pre-suppressed: never kept, never
//    suppress == reference's valid-gating; pool sorted desc -> an all-invalid
//    batch ends the scan; k==100 early stop proven exact (outputs only depend
//    on first 100 kept)
//  * iou>0.6f exact integer form (R2-verified): inter<<25 > 20132661*union
__global__ __launch_bounds__(64) void nms_kernel(const uint4* __restrict__ dec,
                                                 const unsigned long long* __restrict__ pool,
                                                 float* __restrict__ out) {
  __shared__ int4 kbox[MAXDET];
  __shared__ int  karea[MAXDET];
  int img = blockIdx.x;
  int lane = threadIdx.x;

  float* out_s = out + img * MAXDET;
  float* out_c = out + BATCH * MAXDET + img * MAXDET;
  float* out_b = out + 2 * BATCH * MAXDET + img * MAXDET * 4;

  int k = 0;
  bool full = false;

  for (int b0 = 0; b0 < POOLN; b0 += 64) {
    int i = b0 + lane;
    bool inb = i < POOLN;

    float sc = -1.0f;
    int4 bx = make_int4(0, 0, 0, 0);
    int ar = 0;
    unsigned cls = 0;
    if (inb) {
      unsigned long long key = pool[img * POOLN + i];
      unsigned low = (unsigned)key;
      int level = (low >> 20) & 7;
      int idx = low & 0xFFFFF;
      uint4 e = dec[img * NPOS + d_lvl_off[level] + idx];
      sc = __uint_as_float(e.x);
      cls = e.y;
      bx = make_int4((int)(e.z & 0xFFFF), (int)(e.z >> 16),
                     (int)(e.w & 0xFFFF), (int)(e.w >> 16));
      ar = (bx.z - bx.x) * (bx.w - bx.y);
    }

    bool invalid = !(sc > 0.01f);
    if (__all(invalid)) break;          // sorted desc: everything after is invalid too
    bool sup = invalid;

    // vs previously-kept boxes (uniform LDS broadcasts, independent iterations)
    for (int t = 0; t < k; ++t) {
      int4 kb = kbox[t];
      int  ka = karea[t];
      int xx1 = max(bx.x, kb.x), yy1 = max(bx.y, kb.y);
      int xx2 = min(bx.z, kb.z), yy2 = min(bx.w, kb.w);
      int iw = max(xx2 - xx1, 0), ih = max(yy2 - yy1, 0);
      int inter = iw * ih;
      int uni = ar + ka - inter;
      sup = sup || (((long long)inter << 25) > 20132661LL * (long long)uni);
    }

    // in-batch resolve (ascending lane == ascending sorted index)
    unsigned long long alive = __ballot(!sup);
    while (alive) {
      int j = __ffsll(alive) - 1;

      int jx1 = __shfl(bx.x, j, 64), jy1 = __shfl(bx.y, j, 64);
      int jx2 = __shfl(bx.z, j, 64), jy2 = __shfl(bx.w, j, 64);
      int ja  = __shfl(ar,   j, 64);

      if (lane == j) {                  // lane j is kept: record + emit
        kbox[k]  = bx;
        karea[k] = ar;
        out_s[k] = sc;
        out_c[k] = (float)(int)cls;
        out_b[k * 4 + 0] = (float)bx.x;
        out_b[k * 4 + 1] = (float)bx.y;
        out_b[k * 4 + 2] = (float)bx.z;
        out_b[k * 4 + 3] = (float)bx.w;
      }
      ++k;
      if (k == MAXDET) { full = true; break; }

      if (lane > j) {                   // apply j's suppression to later lanes
        int xx1 = max(bx.x, jx1), yy1 = max(bx.y, jy1);
        int xx2 = min(bx.z, jx2), yy2 = min(bx.w, jy2);
        int iw = max(xx2 - xx1, 0), ih = max(yy2 - yy1, 0);
        int inter = iw * ih;
        int uni = ar + ja - inter;
        sup = sup || (((long long)inter << 25) > 20132661LL * (long long)uni);
      }

      unsigned long long himask = (j < 63) ? (~0ULL << (j + 1)) : 0ULL;
      alive = __ballot(!sup) & himask;
    }
    if (full) break;
  }

  for (int s = k + lane; s < MAXDET; s += 64) {
    out_s[s] = -1.0f;
    out_c[s] = -1.0f;
    out_b[s * 4 + 0] = -1.0f;
    out_b[s * 4 + 1] = -1.0f;
    out_b[s * 4 + 2] = -1.0f;
    out_b[s * 4 + 3] = -1.0f;
  }
}

// ---------------- launcher ----------------
extern "C" void kernel_launch(void* const* d_in, const int* in_sizes, int n_in,
                              void* d_out, int out_size, void* d_ws, size_t ws_size,
                              hipStream_t stream) {
  Ptrs args;
  for (int i = 0; i < 20; ++i) args.p[i] = (const float*)d_in[i];

  char* ws = (char*)d_ws;
  uint4* dec = (uint4*)ws;                              // 5,586,944 B
  ws += (size_t)BATCH * NPOS * 16;
  unsigned long long* pool = (unsigned long long*)ws;   // 424,960 B
  ws += (size_t)BATCH * POOLN * 8;
  unsigned long long* gbuf = (unsigned long long*)ws;   // 1,007,616 B (16B-aligned)
  ws += (size_t)BATCH * CAPTOT * 8;
  unsigned* sbuf = (unsigned*)ws;                       // 16*21824*4 = 1,396,736 B
  ws += (size_t)BATCH * NPOS * 4;
  unsigned* ghist = (unsigned*)ws;                      // 48*4096*4 = 786,432 B
  ws += (size_t)BATCH * 3 * NBINS * 4;
  int* gcnt = (int*)ws;                                 // 192 B  (zeroed by decode)
  ws += 192;
  int* bcut = (int*)ws;                                 // 192 B  (written by cutoff)
  float* out = (float*)d_out;

  hipMemsetAsync(ghist, 0, (size_t)BATCH * 3 * NBINS * 4, stream);

  decode_kernel<<<BATCH * DEC_BPI, 256, 0, stream>>>(args, dec, gbuf, gcnt, sbuf);
  hist_kernel<<<BATCH * HIST_TPI, 256, 0, stream>>>(sbuf, ghist);
  cutoff_kernel<<<BATCH * 3, 256, 0, stream>>>(ghist, bcut);
  gather_kernel<<<BATCH * GATHER_BPI, 256, 0, stream>>>(sbuf, bcut, gbuf, gcnt);
  sort_kernel<<<BATCH * 4, 256, 0, stream>>>(gbuf, gcnt);
  pos_kernel<<<BATCH * POS_BPI, 256, 0, stream>>>(gbuf, gcnt, pool);
  nms_kernel<<<BATCH, 64, 0, stream>>>(dec, pool, out);
}